// Round 4
// baseline (159.805 us; speedup 1.0000x reference)
//
#include <hip/hip_runtime.h>

// Involution2d, 3-kernel split.
// x[4,256,64,64] f32, w[784,256] f32, b[784] f32 -> out[4,256,64,64] f32
// K0: convert x, w to bf16 in workspace.
// K1: kern[b][784][4096] = W(784x256) @ x[b](256x4096) + bias   (bf16 MFMA, bf16 out)
// K2: out[b][g*16+cg][p] = sum_{7x7} x[b][g*16+cg][p+off] * kern[b][g*49+koff][p]

#define B_   4
#define C_   256
#define HW_  4096
#define G_   16
#define KK_  49
#define M_   784          // G_*KK_
#define KS_  7
#define PD_  3

#define KERN_BYTES  (B_*M_*HW_*2)            // 25,690,112
#define XBF_BYTES   (B_*C_*HW_*2)            // 8,388,608
#define XBF_OFF     KERN_BYTES
#define WBF_OFF     (KERN_BYTES + XBF_BYTES)

typedef __attribute__((ext_vector_type(8))) short bf16x8;
typedef __attribute__((ext_vector_type(4))) float f32x4;

__device__ inline unsigned f2bf(float f) {            // RNE fp32->bf16
    unsigned u = __float_as_uint(f);
    u += 0x7FFF + ((u >> 16) & 1);
    return u >> 16;
}
__device__ inline float bf2f(unsigned short s) {
    return __uint_as_float(((unsigned)s) << 16);
}

// ---------------- K0: fp32 -> bf16 (x and w) ----------------
#define NXP (B_*C_*HW_/2)     // 2,097,152 dword-pairs
#define NWP (M_*C_/2)         //   100,352
__global__ __launch_bounds__(256)
void cvt_bf16(const float* __restrict__ x, const float* __restrict__ wk,
              unsigned* __restrict__ xbf, unsigned* __restrict__ wbf) {
    int i = blockIdx.x * 256 + threadIdx.x;
    if (i < NXP) {
        float2 v = ((const float2*)x)[i];
        xbf[i] = f2bf(v.x) | (f2bf(v.y) << 16);
    } else if (i < NXP + NWP) {
        int j = i - NXP;
        float2 v = ((const float2*)wk)[j];
        wbf[j] = f2bf(v.x) | (f2bf(v.y) << 16);
    }
}

// ---------------- K1: kern GEMM ----------------
// block: BM=112 (7 m-tiles) x BN=64 (4 waves, 1 n-tile each); K-loop 8 x 32ch.
// grid (nb=64, mb=7, b=4) = 1792 blocks. LDS = 64px x 40 bf16 = 5KB.
__global__ __launch_bounds__(256)
void kern_gemm(const unsigned short* __restrict__ xbf,
               const unsigned short* __restrict__ wbf,
               const float* __restrict__ bk,
               unsigned short* __restrict__ kern) {
    __shared__ unsigned short xT[64 * 40];   // [px][ch] transposed stage, stride 40

    const int nb = blockIdx.x, mb = blockIdx.y, b = blockIdx.z;
    const int p0  = nb * 64;
    const int tid = threadIdx.x;
    const int w    = tid >> 6;
    const int lane = tid & 63;
    const int ln15 = lane & 15;
    const int quad = lane >> 4;
    const int ps = tid & 63;            // staging pixel
    const int cs = (tid >> 6) * 8;      // staging channel offset within chunk

    const unsigned short* xbase = xbf + ((size_t)(b * C_) << 12) + p0 + ps;

    f32x4 acc[7];
    #pragma unroll
    for (int mt = 0; mt < 7; ++mt) acc[mt] = (f32x4){0.f, 0.f, 0.f, 0.f};

    // prefetch chunk 0: 8 bf16, lane-contiguous in pixel (128B/wave segments)
    unsigned short xv[8];
    #pragma unroll
    for (int i = 0; i < 8; ++i) xv[i] = xbase[(size_t)(cs + i) << 12];

    for (int cc = 0; cc < C_; cc += 32) {
        unsigned u0 = (unsigned)xv[0] | ((unsigned)xv[1] << 16);
        unsigned u1 = (unsigned)xv[2] | ((unsigned)xv[3] << 16);
        unsigned u2 = (unsigned)xv[4] | ((unsigned)xv[5] << 16);
        unsigned u3 = (unsigned)xv[6] | ((unsigned)xv[7] << 16);
        *(uint4*)&xT[ps * 40 + cs] = make_uint4(u0, u1, u2, u3);
        __syncthreads();

        if (cc + 32 < C_) {
            #pragma unroll
            for (int i = 0; i < 8; ++i)
                xv[i] = xbase[(size_t)(cc + 32 + cs + i) << 12];
        }

        // B-frag from LDS: B[k=quad*8+j][n=ln15], wave w owns pixels p0+w*16..+15
        bf16x8 bfrag = *(const bf16x8*)&xT[(w * 16 + ln15) * 40 + quad * 8];

        // A-frags straight from bf16 W: A[m=ln15][k=quad*8+j]
        const unsigned short* wbase = wbf + (size_t)(mb * 112 + ln15) * C_ + cc + quad * 8;
        #pragma unroll
        for (int mt = 0; mt < 7; ++mt) {
            bf16x8 afrag = *(const bf16x8*)&wbase[mt * 16 * C_];
            acc[mt] = __builtin_amdgcn_mfma_f32_16x16x32_bf16(afrag, bfrag, acc[mt], 0, 0, 0);
        }
        __syncthreads();
    }

    // epilogue: D[m=quad*4+r][n=ln15]; add bias, store bf16
    const int pcol = p0 + w * 16 + ln15;
    #pragma unroll
    for (int mt = 0; mt < 7; ++mt) {
        #pragma unroll
        for (int r = 0; r < 4; ++r) {
            int m = mb * 112 + mt * 16 + quad * 4 + r;
            float v = acc[mt][r] + bk[m];
            kern[((size_t)(b * M_ + m) << 12) + pcol] = (unsigned short)f2bf(v);
        }
    }
}

// ---------------- K2: apply involution ----------------
// block: 4 rows x 64 px, 8 channels (half group). grid (tile=16, g*2+half=32, b=4) = 2048.
// LDS halo [8][10][72] f32 = 23KB -> 6 blocks/CU.
__global__ __launch_bounds__(256)
void inv_apply(const float* __restrict__ x,
               const unsigned short* __restrict__ kern,
               float* __restrict__ out) {
    __shared__ float halo[8 * 10 * 72];

    const int t    = blockIdx.x;                 // row-tile 0..15
    const int g    = blockIdx.y >> 1;
    const int half = blockIdx.y & 1;
    const int b    = blockIdx.z;
    const int gy0  = t * 4;
    const int tid  = threadIdx.x;
    const int px   = tid & 63;                   // lane == column
    const int py   = tid >> 6;                   // wave == row
    const int c0   = g * 16 + half * 8;

    // 49 kernel values for this pixel: fully coalesced (512B per block per j)
    float kernv[KK_];
    const unsigned short* kb = kern + ((size_t)(b * M_ + g * KK_) << 12) + gy0 * 64 + tid;
    #pragma unroll
    for (int j = 0; j < KK_; ++j) kernv[j] = bf2f(kb[(size_t)j << 12]);

    // stage halo: 8ch x 10 rows x 70 cols (zero-padded), rows contiguous
    for (int e = tid; e < 8 * 10 * 70; e += 256) {
        int ch  = e / 700;
        int rem = e - ch * 700;
        int hy  = rem / 70;
        int hx  = rem - hy * 70;
        int sy  = gy0 + hy - PD_;
        int sx  = hx - PD_;
        float v = 0.f;
        if (sy >= 0 && sy < 64 && sx >= 0 && sx < 64)
            v = x[((size_t)(b * C_ + c0 + ch) << 12) + sy * 64 + sx];
        halo[ch * 720 + hy * 72 + hx] = v;
    }
    __syncthreads();

    #pragma unroll 1
    for (int c = 0; c < 8; ++c) {
        const float* xs = &halo[c * 720 + py * 72 + px];
        float a = 0.f;
        #pragma unroll
        for (int kh = 0; kh < KS_; ++kh) {
            #pragma unroll
            for (int kw = 0; kw < KS_; ++kw) {
                a = fmaf(xs[kh * 72 + kw], kernv[kh * KS_ + kw], a);
            }
        }
        out[((size_t)(b * C_ + c0 + c) << 12) + gy0 * 64 + tid] = a;
    }
}

extern "C" void kernel_launch(void* const* d_in, const int* in_sizes, int n_in,
                              void* d_out, int out_size, void* d_ws, size_t ws_size,
                              hipStream_t stream) {
    const float* x  = (const float*)d_in[0];
    const float* wk = (const float*)d_in[1];
    const float* bk = (const float*)d_in[2];
    float* o = (float*)d_out;

    unsigned short* kern_ws = (unsigned short*)d_ws;
    unsigned*       xbf     = (unsigned*)((char*)d_ws + XBF_OFF);
    unsigned*       wbf     = (unsigned*)((char*)d_ws + WBF_OFF);

    cvt_bf16<<<dim3((NXP + NWP + 255) / 256), dim3(256), 0, stream>>>(x, wk, xbf, wbf);
    kern_gemm<<<dim3(64, 7, B_), dim3(256), 0, stream>>>(
        (const unsigned short*)xbf, (const unsigned short*)wbf, bk, kern_ws);
    inv_apply<<<dim3(16, 32, B_), dim3(256), 0, stream>>>(x, kern_ws, o);
}